// Round 12
// baseline (1289.169 us; speedup 1.0000x reference)
//
#include <hip/hip_runtime.h>
#include <stdint.h>

typedef unsigned short u16;
typedef unsigned int u32;
typedef __attribute__((ext_vector_type(8))) short s16x8;
typedef __attribute__((ext_vector_type(4))) float f32x4;

#define P_ 256
#define L_ 64
#define IDIM 512
#define H_ 1024
#define PH (P_ * H_)

__device__ __forceinline__ u16 f2bf(float f){union{float f;u32 u;}v;v.f=f;u32 u=v.u;return (u16)((u+0x7FFFu+((u>>16)&1u))>>16);}
__device__ __forceinline__ float sigf(float x){return 1.0f/(1.0f+__expf(-x));}
__device__ __forceinline__ float tanhf_(float x){return 1.0f-2.0f/(__expf(2.0f*x)+1.0f);}

__device__ __forceinline__ s16x8 pack8v(float4 a, float4 b){
  s16x8 r;
  r[0]=(short)f2bf(a.x); r[1]=(short)f2bf(a.y); r[2]=(short)f2bf(a.z); r[3]=(short)f2bf(a.w);
  r[4]=(short)f2bf(b.x); r[5]=(short)f2bf(b.y); r[6]=(short)f2bf(b.z); r[7]=(short)f2bf(b.w);
  return r;
}
__device__ __forceinline__ s16x8 pack8(const float* s){
  return pack8v(*(const float4*)s, *(const float4*)(s+4));
}
// 16B write-through store (bypasses L2 -> coherent at IF$)
__device__ __forceinline__ void st16_coh(u16* addr, s16x8 v){
  asm volatile("global_store_dwordx4 %0, %1, off sc0 sc1" :: "v"(addr), "v"(v) : "memory");
}
// paired 2-lane bf16 -> one 32-bit write-through store
__device__ __forceinline__ void st_pair(u16* addr, float hv, int lane){
  u32 b = (u32)f2bf(hv);
  u32 other = __shfl_xor(b, 1);
  if ((lane & 1) == 0) {
    u32 w = b | (other << 16);
    __hip_atomic_store((u32*)addr, w, __ATOMIC_RELAXED, __HIP_MEMORY_SCOPE_AGENT);
  }
}
__device__ __forceinline__ void set_flag(u32* f, u32 v){
  __hip_atomic_store(f, v, __ATOMIC_RELAXED, __HIP_MEMORY_SCOPE_AGENT);
}
// wave0: lane l polls flag[l] of a group (PACKED layout - R11 spreading regressed)
__device__ __forceinline__ void poll_flags(u32* fg, u32 target, int wid, int lane){
  if (wid == 0) {
    for (;;) {
      u32 f = __hip_atomic_load(&fg[lane], __ATOMIC_RELAXED, __HIP_MEMORY_SCOPE_AGENT);
      if (__all((int)(f >= target))) break;
      __builtin_amdgcn_s_sleep(1);
    }
  }
  asm volatile("" ::: "memory");
  __syncthreads();
}

// Persistent kernel: 128 blocks = 2 pair-sets x 64 unit-blocks.
// Block (pairsel, jb) runs TWO independent recurrences (groups pairsel, pairsel+2)
// in staggered phases: group A's publish->poll RTT hides under group B's phase.
__global__ void __launch_bounds__(256, 1)
tagger_net(const int* __restrict__ paths, const int* __restrict__ lengths,
           const float* __restrict__ emb,
           const float* __restrict__ Wih, const float* __restrict__ Whh,
           const float* __restrict__ bih, const float* __restrict__ bhh,
           const float* __restrict__ Win, const float* __restrict__ bin,
           const float* __restrict__ Wout, const float* __restrict__ bout,
           const float* __restrict__ Wlin, const float* __restrict__ blin,
           u16* __restrict__ X, u16* __restrict__ Hbuf,
           u16* __restrict__ vbuf, float* __restrict__ pmax,
           u32* flags, float* __restrict__ out)
{
  __shared__ __align__(16) float S[16384];   // 64 KB K-reduction scratch
  const int tid  = threadIdx.x;
  const int wid  = tid >> 6, lane = tid & 63;
  const int lrow = lane & 15, lgrp = lane >> 4;
  const int bid  = blockIdx.x;
  const int pairsel = bid & 1, jb = bid >> 1;
  const int p0A = pairsel * 64, p0B = p0A + 128;
  const int j0 = jb * 16;
  u32* fgA = flags + pairsel * 64;
  u32* fgB = flags + (pairsel + 2) * 64;
  u32* mfA = fgA + jb;
  u32* mfB = fgB + jb;

  // ---- init: gather X[t=jb] rows + zero Hbuf[0] chunks for BOTH groups ----
#pragma unroll
  for (int gh = 0; gh < 2; ++gh) {
    const int pg = gh ? p0B : p0A;
    for (int it = 0; it < 16; ++it) {
      int e = (it * 256 + tid) * 8;
      int row = e >> 9, col = e & 511;
      int tok = paths[(pg + row) * L_ + jb];
      const float* s = emb + (size_t)tok * IDIM + col;
      st16_coh(X + ((size_t)jb * P_ + pg + row) * IDIM + col,
               pack8v(*(const float4*)s, *(const float4*)(s + 4)));
    }
#pragma unroll
    for (int i = 0; i < 2; ++i) {
      int idx = tid * 2 + i;
      int row = idx >> 3, cp = idx & 7;
      __hip_atomic_store((u32*)&Hbuf[(size_t)(pg + row) * H_ + j0 + cp * 2], 0u,
                         __ATOMIC_RELAXED, __HIP_MEMORY_SCOPE_AGENT);
    }
  }
  __syncthreads();                            // drains vmcnt of all waves
  if (tid == 0) { set_flag(mfA, 1u); set_flag(mfB, 1u); }

  // ---- weights into registers: wave wid owns K chunks c = wid + 4*i ----
  s16x8 breg[12][4];
#pragma unroll
  for (int i = 0; i < 12; ++i) {
    const int k = (wid + 4 * i) * 32 + lgrp * 8;
#pragma unroll
    for (int fn = 0; fn < 4; ++fn) {
      const int n = fn * H_ + j0 + lrow;
      const float* src = (k < IDIM) ? (Wih + (size_t)n * IDIM + k)
                                    : (Whh + (size_t)n * H_ + (k - IDIM));
      breg[i][fn] = pack8(src);
    }
  }

  const int prow_off = wid * 16 + lgrp * 4;
  int lenrA[4], lenrB[4]; float biasv[4];
#pragma unroll
  for (int r2 = 0; r2 < 4; ++r2) {
    lenrA[r2] = lengths[p0A + prow_off + r2];
    lenrB[r2] = lengths[p0B + prow_off + r2];
  }
#pragma unroll
  for (int fn = 0; fn < 4; ++fn) {
    int n = fn * H_ + j0 + lrow;
    biasv[fn] = bih[n] + bhh[n];
  }
  float cstA[4] = {0.f,0.f,0.f,0.f}, hstA[4] = {0.f,0.f,0.f,0.f};
  float cstB[4] = {0.f,0.f,0.f,0.f}, hstB[4] = {0.f,0.f,0.f,0.f};

  // One full LSTM step for one group (R9 step body, parametrized).
#define PHASE(T, PG, FG, MF, CST, HST, LENR) do {                              \
    poll_flags(FG, (u32)((T) + 1), wid, lane);                                 \
    const u16* Xt_ = X + (size_t)(T) * (P_ * IDIM)                             \
                     + (size_t)((PG) + lrow) * IDIM + lgrp * 8;                \
    const u16* Hp_ = Hbuf + (size_t)(T) * PH                                   \
                     + (size_t)((PG) + lrow) * H_ + lgrp * 8;                  \
    u16* Hw_ = Hbuf + (size_t)((T) + 1) * PH;                                  \
    f32x4 acc[4][4];                                                           \
    _Pragma("unroll") for (int a_ = 0; a_ < 4; ++a_)                           \
      _Pragma("unroll") for (int b_ = 0; b_ < 4; ++b_)                         \
        _Pragma("unroll") for (int e_ = 0; e_ < 4; ++e_) acc[a_][b_][e_] = 0.f;\
    s16x8 fx_[4][4];                                                           \
    _Pragma("unroll") for (int i_ = 0; i_ < 4; ++i_) {                         \
      const int k0_ = wid * 32 + i_ * 128;                                     \
      _Pragma("unroll") for (int fm_ = 0; fm_ < 4; ++fm_)                      \
        fx_[i_][fm_] = *(const s16x8*)(Xt_ + (size_t)fm_ * (16 * IDIM) + k0_); \
    }                                                                          \
    _Pragma("unroll") for (int i_ = 0; i_ < 4; ++i_)                           \
      _Pragma("unroll") for (int fm_ = 0; fm_ < 4; ++fm_)                      \
        _Pragma("unroll") for (int fn_ = 0; fn_ < 4; ++fn_)                    \
          acc[fm_][fn_] = __builtin_amdgcn_mfma_f32_16x16x32_bf16(             \
              fx_[i_][fm_], breg[i_][fn_], acc[fm_][fn_], 0, 0, 0);            \
    _Pragma("unroll") for (int half_ = 0; half_ < 2; ++half_) {                \
      s16x8 fh_[4][4];                                                         \
      _Pragma("unroll") for (int i_ = 0; i_ < 4; ++i_) {                       \
        const int kh_ = wid * 32 + (half_ * 4 + i_) * 128;                     \
        _Pragma("unroll") for (int fm_ = 0; fm_ < 4; ++fm_)                    \
          fh_[i_][fm_] = *(const s16x8*)(Hp_ + (size_t)fm_ * (16 * H_) + kh_); \
      }                                                                        \
      _Pragma("unroll") for (int i_ = 0; i_ < 4; ++i_)                         \
        _Pragma("unroll") for (int fm_ = 0; fm_ < 4; ++fm_)                    \
          _Pragma("unroll") for (int fn_ = 0; fn_ < 4; ++fn_)                  \
            acc[fm_][fn_] = __builtin_amdgcn_mfma_f32_16x16x32_bf16(           \
                fh_[i_][fm_], breg[4 + half_ * 4 + i_][fn_], acc[fm_][fn_],    \
                0, 0, 0);                                                      \
    }                                                                          \
    _Pragma("unroll") for (int fm_ = 0; fm_ < 4; ++fm_)                        \
      _Pragma("unroll") for (int fn_ = 0; fn_ < 4; ++fn_)                      \
        *(f32x4*)&S[((wid * 16) + fm_ * 4 + fn_) * 256 + lane * 4]             \
            = acc[fm_][fn_];                                                   \
    __syncthreads();                                                           \
    f32x4 red[4];                                                              \
    _Pragma("unroll") for (int fn_ = 0; fn_ < 4; ++fn_) {                      \
      red[fn_] = *(const f32x4*)&S[(wid * 4 + fn_) * 256 + lane * 4];          \
      _Pragma("unroll") for (int w_ = 1; w_ < 4; ++w_)                         \
        red[fn_] += *(const f32x4*)&S[(w_ * 16 + wid * 4 + fn_) * 256          \
                                      + lane * 4];                             \
    }                                                                          \
    _Pragma("unroll") for (int r_ = 0; r_ < 4; ++r_) {                         \
      if ((T) < (LENR)[r_]) {                                                  \
        float gi = red[0][r_] + biasv[0];                                      \
        float gf = red[1][r_] + biasv[1];                                      \
        float gg = red[2][r_] + biasv[2];                                      \
        float go = red[3][r_] + biasv[3];                                      \
        float cn = sigf(gf) * (CST)[r_] + sigf(gi) * tanhf_(gg);               \
        (CST)[r_] = cn;                                                        \
        (HST)[r_] = sigf(go) * tanhf_(cn);                                     \
      }                                                                        \
      st_pair(&Hw_[(size_t)((PG) + prow_off + r_) * H_ + j0 + lrow],           \
              (HST)[r_], lane);                                                \
    }                                                                          \
    __syncthreads();                                                           \
    if (tid == 0) set_flag(MF, (u32)((T) + 2));                                \
  } while (0)

  for (int t = 0; t < L_; ++t) {
    PHASE(t, p0A, fgA, mfA, cstA, hstA, lenrA);   // A's RTT hides under B's phase
    PHASE(t, p0B, fgB, mfB, cstB, hstB, lenrB);   // B's RTT hides under next A
  }

  // ================= tail =================
  const u16* hfin = Hbuf + (size_t)L_ * PH;
  poll_flags(fgA, 65u, wid, lane);
  poll_flags(fgB, 65u, wid, lane);

  // ---- v = h@Wv^T + bv (both groups) ----
#define VGEMM(PG) do {                                                         \
    f32x4 a2[4];                                                               \
    _Pragma("unroll") for (int a_ = 0; a_ < 4; ++a_)                           \
      _Pragma("unroll") for (int e_ = 0; e_ < 4; ++e_) a2[a_][e_] = 0.f;       \
    const u16* hp_ = hfin + (size_t)((PG) + lrow) * H_ + lgrp * 8;             \
    const float* wv_ = Win + (size_t)(2 * H_ + j0 + lrow) * H_;                \
    _Pragma("unroll") for (int ic_ = 0; ic_ < 8; ++ic_) {                      \
      const int k0_ = wid * 256 + ic_ * 32;                                    \
      s16x8 fb_ = pack8(wv_ + k0_ + lgrp * 8);                                 \
      _Pragma("unroll") for (int fm_ = 0; fm_ < 4; ++fm_) {                    \
        s16x8 fa_ = *(const s16x8*)(hp_ + (size_t)fm_ * (16 * H_) + k0_);      \
        a2[fm_] = __builtin_amdgcn_mfma_f32_16x16x32_bf16(fa_, fb_, a2[fm_],   \
                                                          0, 0, 0);            \
      }                                                                        \
    }                                                                          \
    _Pragma("unroll") for (int fm_ = 0; fm_ < 4; ++fm_)                        \
      *(f32x4*)&S[(wid * 4 + fm_) * 256 + lane * 4] = a2[fm_];                 \
    __syncthreads();                                                           \
    f32x4 rv_ = *(const f32x4*)&S[(wid) * 256 + lane * 4];                     \
    _Pragma("unroll") for (int w_ = 1; w_ < 4; ++w_)                           \
      rv_ += *(const f32x4*)&S[(w_ * 4 + wid) * 256 + lane * 4];               \
    float bvj_ = bin[2 * H_ + j0 + lrow];                                      \
    _Pragma("unroll") for (int r_ = 0; r_ < 4; ++r_)                           \
      st_pair(&vbuf[(size_t)((PG) + prow_off + r_) * H_ + j0 + lrow],          \
              rv_[r_] + bvj_, lane);                                           \
    __syncthreads();                                                           \
  } while (0)

  VGEMM(p0A);
  VGEMM(p0B);
  if (tid == 0) { set_flag(mfA, 66u); set_flag(mfB, 66u); }
  poll_flags(fgA, 66u, wid, lane);
  poll_flags(fgB, 66u, wid, lane);

  // ---- attn = v@Wout^T + bout, per-block max over 64 rows (both groups) ----
#define ATTN(PG, GIDX) do {                                                    \
    f32x4 a2[4];                                                               \
    _Pragma("unroll") for (int a_ = 0; a_ < 4; ++a_)                           \
      _Pragma("unroll") for (int e_ = 0; e_ < 4; ++e_) a2[a_][e_] = 0.f;       \
    const u16* vp_ = vbuf + (size_t)((PG) + lrow) * H_ + lgrp * 8;             \
    const float* wo_ = Wout + (size_t)(j0 + lrow) * H_;                        \
    _Pragma("unroll") for (int ic_ = 0; ic_ < 8; ++ic_) {                      \
      const int k0_ = wid * 256 + ic_ * 32;                                    \
      s16x8 fb_ = pack8(wo_ + k0_ + lgrp * 8);                                 \
      _Pragma("unroll") for (int fm_ = 0; fm_ < 4; ++fm_) {                    \
        s16x8 fa_ = *(const s16x8*)(vp_ + (size_t)fm_ * (16 * H_) + k0_);      \
        a2[fm_] = __builtin_amdgcn_mfma_f32_16x16x32_bf16(fa_, fb_, a2[fm_],   \
                                                          0, 0, 0);            \
      }                                                                        \
    }                                                                          \
    _Pragma("unroll") for (int fm_ = 0; fm_ < 4; ++fm_)                        \
      *(f32x4*)&S[(wid * 4 + fm_) * 256 + lane * 4] = a2[fm_];                 \
    __syncthreads();                                                           \
    f32x4 rv_ = *(const f32x4*)&S[(wid) * 256 + lane * 4];                     \
    _Pragma("unroll") for (int w_ = 1; w_ < 4; ++w_)                           \
      rv_ += *(const f32x4*)&S[(w_ * 4 + wid) * 256 + lane * 4];               \
    float m_ = fmaxf(fmaxf(rv_[0], rv_[1]), fmaxf(rv_[2], rv_[3]))             \
               + bout[j0 + lrow];                                              \
    __syncthreads();                                                           \
    S[(wid * 4 + lgrp) * 16 + lrow] = m_;                                      \
    __syncthreads();                                                           \
    if (tid < 16) {                                                            \
      float mx_ = S[tid];                                                      \
      _Pragma("unroll") for (int s_ = 1; s_ < 16; ++s_)                        \
        mx_ = fmaxf(mx_, S[s_ * 16 + tid]);                                    \
      __hip_atomic_store(&pmax[(size_t)(GIDX) * H_ + j0 + tid], mx_,           \
                         __ATOMIC_RELAXED, __HIP_MEMORY_SCOPE_AGENT);          \
    }                                                                          \
    __syncthreads();                                                           \
  } while (0)

  ATTN(p0A, pairsel);
  ATTN(p0B, pairsel + 2);
  if (tid == 0) { set_flag(mfA, 67u); set_flag(mfB, 67u); }

  if (bid != 0) return;

  // ---- final: max over 4 groups, 1024->2 dot, sigmoid ----
  if (wid == 0) {
    for (int g2 = 0; g2 < 4; ++g2) {
      for (;;) {
        u32 f = __hip_atomic_load(&flags[g2 * 64 + lane], __ATOMIC_RELAXED, __HIP_MEMORY_SCOPE_AGENT);
        if (__all((int)(f >= 67u))) break;
        __builtin_amdgcn_s_sleep(1);
      }
    }
  }
  asm volatile("" ::: "memory");
  __syncthreads();
  {
    int j4 = tid * 4;
    float s0 = 0.f, s1 = 0.f;
#pragma unroll
    for (int e = 0; e < 4; ++e) {
      float pv = pmax[j4 + e];
#pragma unroll
      for (int gg2 = 1; gg2 < 4; ++gg2) pv = fmaxf(pv, pmax[gg2 * H_ + j4 + e]);
      s0 += pv * Wlin[j4 + e];
      s1 += pv * Wlin[H_ + j4 + e];
    }
    S[tid] = s0; S[256 + tid] = s1;
    __syncthreads();
    for (int s2 = 128; s2 > 0; s2 >>= 1) {
      if (tid < s2) { S[tid] += S[tid + s2]; S[256 + tid] += S[256 + tid + s2]; }
      __syncthreads();
    }
    if (tid == 0) {
      out[0] = sigf(S[0] + blin[0]);
      out[1] = sigf(S[256] + blin[1]);
    }
  }
}

extern "C" void kernel_launch(void* const* d_in, const int* in_sizes, int n_in,
                              void* d_out, int out_size, void* d_ws, size_t ws_size,
                              hipStream_t stream) {
  const int*   paths   = (const int*)d_in[0];
  const int*   lengths = (const int*)d_in[1];
  const float* emb     = (const float*)d_in[2];
  const float* Wih     = (const float*)d_in[3];
  const float* Whh     = (const float*)d_in[4];
  const float* bih     = (const float*)d_in[5];
  const float* bhh     = (const float*)d_in[6];
  const float* Win     = (const float*)d_in[7];
  const float* bin     = (const float*)d_in[8];
  const float* Wout    = (const float*)d_in[9];
  const float* bout    = (const float*)d_in[10];
  const float* Wlin    = (const float*)d_in[11];
  const float* blin    = (const float*)d_in[12];
  float* out = (float*)d_out;

  char* ws = (char*)d_ws;
  u32*   flags  = (u32*)  (ws);                  //      1,024 (4 groups x 64 packed flags)
  float* pmax   = (float*)(ws + 4096);           //     16,384
  u16*   X      = (u16*)  (ws + 32768);          // 16,777,216
  u16*   Hbuf   = (u16*)  (ws + 16810240);       // 65 x 524,288 = 34,078,720
  u16*   vbuf   = (u16*)  (ws + 50888960);       //    524,288   (total ~51.4 MB)

  hipMemsetAsync(flags, 0, 1024, stream);
  tagger_net<<<128, 256, 0, stream>>>(paths, lengths, emb, Wih, Whh, bih, bhh,
                                      Win, bin, Wout, bout, Wlin, blin,
                                      X, Hbuf, vbuf, pmax, flags, out);
}

// Round 13
// 615.955 us; speedup vs baseline: 2.0930x; 2.0930x over previous
//
#include <hip/hip_runtime.h>
#include <stdint.h>

typedef unsigned short u16;
typedef unsigned int u32;
typedef __attribute__((ext_vector_type(8))) short s16x8;
typedef __attribute__((ext_vector_type(4))) float f32x4;
typedef __attribute__((ext_vector_type(4))) unsigned int u32x4;

#define P_ 256
#define L_ 64
#define IDIM 512
#define H_ 1024
#define PH (P_ * H_)

__device__ __forceinline__ u16 f2bf(float f){union{float f;u32 u;}v;v.f=f;u32 u=v.u;return (u16)((u+0x7FFFu+((u>>16)&1u))>>16);}
__device__ __forceinline__ float sigf(float x){return 1.0f/(1.0f+__expf(-x));}
__device__ __forceinline__ float tanhf_(float x){return 1.0f-2.0f/(__expf(2.0f*x)+1.0f);}

__device__ __forceinline__ s16x8 pack8v(float4 a, float4 b){
  s16x8 r;
  r[0]=(short)f2bf(a.x); r[1]=(short)f2bf(a.y); r[2]=(short)f2bf(a.z); r[3]=(short)f2bf(a.w);
  r[4]=(short)f2bf(b.x); r[5]=(short)f2bf(b.y); r[6]=(short)f2bf(b.z); r[7]=(short)f2bf(b.w);
  return r;
}
__device__ __forceinline__ s16x8 pack8(const float* s){
  return pack8v(*(const float4*)s, *(const float4*)(s+4));
}
// 16B write-through store (bypasses L2 -> coherent at IF$)
__device__ __forceinline__ void st16_coh(u16* addr, s16x8 v){
  asm volatile("global_store_dwordx4 %0, %1, off sc0 sc1" :: "v"(addr), "v"(v) : "memory");
}
// 16B coherent load (bypasses L1/L2 -> reads IF$ directly)
__device__ __forceinline__ s16x8 ld16_coh(const u16* a){
  s16x8 v;
  asm volatile("global_load_dwordx4 %0, %1, off sc0 sc1" : "=v"(v) : "v"(a) : "memory");
  return v;
}
// sentinel test: any u32 pair still 0xFFFFFFFF (bf16 -NaN pair, never produced)
__device__ __forceinline__ u32 frag_bad(s16x8 v){
  u32x4 w = __builtin_bit_cast(u32x4, v);
  return (u32)((w[0]==0xFFFFFFFFu)|(w[1]==0xFFFFFFFFu)|(w[2]==0xFFFFFFFFu)|(w[3]==0xFFFFFFFFu));
}
// paired 2-lane bf16 -> one 32-bit write-through store
__device__ __forceinline__ void st_pair(u16* addr, float hv, int lane){
  u32 b = (u32)f2bf(hv);
  u32 other = __shfl_xor(b, 1);
  if ((lane & 1) == 0) {
    u32 w = b | (other << 16);
    __hip_atomic_store((u32*)addr, w, __ATOMIC_RELAXED, __HIP_MEMORY_SCOPE_AGENT);
  }
}
__device__ __forceinline__ void set_flag(u32* f, u32 v){
  __hip_atomic_store(f, v, __ATOMIC_RELAXED, __HIP_MEMORY_SCOPE_AGENT);
}
// wave0: lane l polls flag[l] of own group (init/tail only now)
__device__ __forceinline__ void poll_flags(u32* fg, u32 target, int wid, int lane){
  if (wid == 0) {
    for (;;) {
      u32 f = __hip_atomic_load(&fg[lane], __ATOMIC_RELAXED, __HIP_MEMORY_SCOPE_AGENT);
      if (__all((int)(f >= target))) break;
      __builtin_amdgcn_s_sleep(1);
    }
  }
  asm volatile("" ::: "memory");
  __syncthreads();
}

// Persistent kernel: 256 blocks = 4 path-groups x 64 unit-blocks (16 units x 4 gates).
// H publication is SELF-SYNCHRONIZING: renamed Hbuf[t] poisoned with 0xFFFF sentinel at
// init; consumers spin on coherent (sc0 sc1) loads until data lands. No per-step flags.
__global__ void __launch_bounds__(256, 1)
tagger_net(const int* __restrict__ paths, const int* __restrict__ lengths,
           const float* __restrict__ emb,
           const float* __restrict__ Wih, const float* __restrict__ Whh,
           const float* __restrict__ bih, const float* __restrict__ bhh,
           const float* __restrict__ Win, const float* __restrict__ bin,
           const float* __restrict__ Wout, const float* __restrict__ bout,
           const float* __restrict__ Wlin, const float* __restrict__ blin,
           u16* __restrict__ X, u16* __restrict__ Hbuf,
           u16* __restrict__ vbuf, float* __restrict__ pmax,
           u32* flags, float* __restrict__ out)
{
  __shared__ __align__(16) float S[16384];   // 64 KB K-reduction scratch
  const int tid  = threadIdx.x;
  const int wid  = tid >> 6, lane = tid & 63;
  const int lrow = lane & 15, lgrp = lane >> 4;
  const int bid  = blockIdx.x;
  const int g = bid & 3, jb = bid >> 2;      // XCD-clustered group mapping (R9)
  const int p0 = g * 64, j0 = jb * 16;
  u32* fgrp = flags + g * 64;
  u32* myflag = fgrp + jb;

  // ---- init: gather X[t=jb] (write-through); zero own Hbuf[0] chunk;
  //      poison own slice of Hbuf[1..64] with sentinel (write-through) ----
  for (int it = 0; it < 16; ++it) {
    int e = (it * 256 + tid) * 8;
    int row = e >> 9, col = e & 511;
    int tok = paths[(p0 + row) * L_ + jb];
    const float* s = emb + (size_t)tok * IDIM + col;
    st16_coh(X + ((size_t)jb * P_ + p0 + row) * IDIM + col,
             pack8v(*(const float4*)s, *(const float4*)(s + 4)));
  }
#pragma unroll
  for (int i = 0; i < 2; ++i) {
    int idx = tid * 2 + i;
    int row = idx >> 3, cp = idx & 7;
    __hip_atomic_store((u32*)&Hbuf[(size_t)(p0 + row) * H_ + j0 + cp * 2], 0u,
                       __ATOMIC_RELAXED, __HIP_MEMORY_SCOPE_AGENT);
  }
  {
    s16x8 sv;
#pragma unroll
    for (int k2 = 0; k2 < 8; ++k2) sv[k2] = (short)0xFFFF;
    for (int it = 0; it < 32; ++it) {
      int idx = it * 256 + tid;              // 8192 = 64 bufs x 64 rows x 2 chunks
      int buf = idx >> 7;
      int rr  = (idx >> 1) & 63;
      int cc  = (idx & 1) * 8;
      st16_coh(Hbuf + (size_t)(buf + 1) * PH + (size_t)(p0 + rr) * H_ + j0 + cc, sv);
    }
  }
  __syncthreads();                            // drains vmcnt of all waves
  if (tid == 0) set_flag(myflag, 1u);

  // ---- weights into registers: wave wid owns K chunks c = wid + 4*i ----
  s16x8 breg[12][4];
#pragma unroll
  for (int i = 0; i < 12; ++i) {
    const int k = (wid + 4 * i) * 32 + lgrp * 8;
#pragma unroll
    for (int fn = 0; fn < 4; ++fn) {
      const int n = fn * H_ + j0 + lrow;
      const float* src = (k < IDIM) ? (Wih + (size_t)n * IDIM + k)
                                    : (Whh + (size_t)n * H_ + (k - IDIM));
      breg[i][fn] = pack8(src);
    }
  }

  const int prow = p0 + wid * 16 + lgrp * 4;
  int lenr[4]; float biasv[4];
#pragma unroll
  for (int r2 = 0; r2 < 4; ++r2) lenr[r2] = lengths[prow + r2];
#pragma unroll
  for (int fn = 0; fn < 4; ++fn) {
    int n = fn * H_ + j0 + lrow;
    biasv[fn] = bih[n] + bhh[n];
  }
  float cst[4] = {0.f,0.f,0.f,0.f}, hst[4] = {0.f,0.f,0.f,0.f};

  poll_flags(fgrp, 1u, wid, lane);            // init done: X gathered, H0 zeroed, poison set

  const size_t aX = (size_t)(p0 + lrow) * IDIM + lgrp * 8;
  const size_t aH = (size_t)(p0 + lrow) * H_   + lgrp * 8;

  s16x8 fx[4][4];
#define LOADX(T) do { \
    const u16* Xt_ = X + (size_t)(T) * (P_ * IDIM) + aX; \
    _Pragma("unroll") \
    for (int i_ = 0; i_ < 4; ++i_) { \
      const int k0_ = wid * 32 + i_ * 128; \
      _Pragma("unroll") \
      for (int fm_ = 0; fm_ < 4; ++fm_) \
        fx[i_][fm_] = *(const s16x8*)(Xt_ + (size_t)fm_ * (16 * IDIM) + k0_); \
    } } while (0)

  LOADX(0);

  for (int t = 0; t < L_; ++t) {
    const u16* Hr = Hbuf + (size_t)t * PH;
    u16*       Hw = Hbuf + (size_t)(t + 1) * PH;

    f32x4 acc[4][4];
#pragma unroll
    for (int a = 0; a < 4; ++a)
#pragma unroll
      for (int b = 0; b < 4; ++b)
#pragma unroll
        for (int e = 0; e < 4; ++e) acc[a][b][e] = 0.0f;

    // ---- X phase (independent; overlaps siblings still finishing t-1) ----
#pragma unroll
    for (int i = 0; i < 4; ++i)
#pragma unroll
      for (int fm = 0; fm < 4; ++fm)
#pragma unroll
        for (int fn = 0; fn < 4; ++fn)
          acc[fm][fn] = __builtin_amdgcn_mfma_f32_16x16x32_bf16(fx[i][fm], breg[i][fn], acc[fm][fn], 0, 0, 0);

    // ---- H phase: self-synchronizing coherent loads (spin on sentinel) ----
    const u16* Hp = Hr + aH;
#pragma unroll
    for (int half = 0; half < 2; ++half) {
      s16x8 fh[4][4];
      for (;;) {
#pragma unroll
        for (int i = 0; i < 4; ++i) {
          const int kh = wid * 32 + (half * 4 + i) * 128;
#pragma unroll
          for (int fm = 0; fm < 4; ++fm)
            fh[i][fm] = ld16_coh(Hp + (size_t)fm * (16 * H_) + kh);
        }
        asm volatile("s_waitcnt vmcnt(0)" ::: "memory");
        __builtin_amdgcn_sched_barrier(0);
        u32 bad = 0;
#pragma unroll
        for (int i = 0; i < 4; ++i)
#pragma unroll
          for (int fm = 0; fm < 4; ++fm)
            bad |= frag_bad(fh[i][fm]);
        if (!__any((int)bad)) break;
        __builtin_amdgcn_s_sleep(2);          // backoff: bound IF$ spin pressure
      }
#pragma unroll
      for (int i = 0; i < 4; ++i)
#pragma unroll
        for (int fm = 0; fm < 4; ++fm)
#pragma unroll
          for (int fn = 0; fn < 4; ++fn)
            acc[fm][fn] = __builtin_amdgcn_mfma_f32_16x16x32_bf16(fh[i][fm], breg[4 + half * 4 + i][fn], acc[fm][fn], 0, 0, 0);
    }

    const int tp1 = (t < L_ - 1) ? (t + 1) : (L_ - 1);
    LOADX(tp1);                               // prefetch next X under reduce/epilogue

    // ---- cross-wave K-reduction ----
#pragma unroll
    for (int fm = 0; fm < 4; ++fm)
#pragma unroll
      for (int fn = 0; fn < 4; ++fn)
        *(f32x4*)&S[((wid * 16) + fm * 4 + fn) * 256 + lane * 4] = acc[fm][fn];
    __syncthreads();
    f32x4 red[4];
#pragma unroll
    for (int fn = 0; fn < 4; ++fn) {
      red[fn] = *(const f32x4*)&S[(wid * 4 + fn) * 256 + lane * 4];
#pragma unroll
      for (int w = 1; w < 4; ++w)
        red[fn] += *(const f32x4*)&S[(w * 16 + wid * 4 + fn) * 256 + lane * 4];
    }

    // ---- in-register gate epilogue; fire-and-forget write-through H ----
#pragma unroll
    for (int r2 = 0; r2 < 4; ++r2) {
      if (t < lenr[r2]) {
        float gi = red[0][r2] + biasv[0];
        float gf = red[1][r2] + biasv[1];
        float gg = red[2][r2] + biasv[2];
        float go = red[3][r2] + biasv[3];
        float cn = sigf(gf) * cst[r2] + sigf(gi) * tanhf_(gg);
        cst[r2] = cn;
        hst[r2] = sigf(go) * tanhf_(cn);
      }
      st_pair(&Hw[(size_t)(prow + r2) * H_ + j0 + lrow], hst[r2], lane);
    }
    __syncthreads();                          // protect S reuse (drains under overlap)
  }

  // ================= tail =================
  // own stores drained by final __syncthreads; publish completion
  if (tid == 0) set_flag(myflag, 2u);
  const u16* hfin = Hbuf + (size_t)L_ * PH;
  poll_flags(fgrp, 2u, wid, lane);

  // ---- v = h@Wv^T + bv ----
  {
    f32x4 acc2[4];
#pragma unroll
    for (int a = 0; a < 4; ++a)
#pragma unroll
      for (int e = 0; e < 4; ++e) acc2[a][e] = 0.0f;
    const u16* hp = hfin + aH;
    const float* wv = Win + (size_t)(2 * H_ + j0 + lrow) * H_;
#pragma unroll
    for (int ic = 0; ic < 8; ++ic) {
      const int k0 = wid * 256 + ic * 32;
      s16x8 fbv = pack8(wv + k0 + lgrp * 8);
#pragma unroll
      for (int fm = 0; fm < 4; ++fm) {
        s16x8 fav = *(const s16x8*)(hp + (size_t)fm * (16 * H_) + k0);
        acc2[fm] = __builtin_amdgcn_mfma_f32_16x16x32_bf16(fav, fbv, acc2[fm], 0, 0, 0);
      }
    }
#pragma unroll
    for (int fm = 0; fm < 4; ++fm)
      *(f32x4*)&S[(wid * 4 + fm) * 256 + lane * 4] = acc2[fm];
    __syncthreads();
    f32x4 rv = *(const f32x4*)&S[(wid) * 256 + lane * 4];
#pragma unroll
    for (int w = 1; w < 4; ++w)
      rv += *(const f32x4*)&S[(w * 4 + wid) * 256 + lane * 4];
    float bvj = bin[2 * H_ + j0 + lrow];
#pragma unroll
    for (int r2 = 0; r2 < 4; ++r2)
      st_pair(&vbuf[(size_t)(prow + r2) * H_ + j0 + lrow], rv[r2] + bvj, lane);
  }
  __syncthreads();
  if (tid == 0) set_flag(myflag, 3u);
  poll_flags(fgrp, 3u, wid, lane);

  // ---- attn = v@Wout^T + bout, then per-block max over own 64 rows ----
  {
    f32x4 acc2[4];
#pragma unroll
    for (int a = 0; a < 4; ++a)
#pragma unroll
      for (int e = 0; e < 4; ++e) acc2[a][e] = 0.0f;
    const u16* vp = vbuf + aH;
    const float* wo = Wout + (size_t)(j0 + lrow) * H_;
#pragma unroll
    for (int ic = 0; ic < 8; ++ic) {
      const int k0 = wid * 256 + ic * 32;
      s16x8 fbv = pack8(wo + k0 + lgrp * 8);
#pragma unroll
      for (int fm = 0; fm < 4; ++fm) {
        s16x8 fav = *(const s16x8*)(vp + (size_t)fm * (16 * H_) + k0);
        acc2[fm] = __builtin_amdgcn_mfma_f32_16x16x32_bf16(fav, fbv, acc2[fm], 0, 0, 0);
      }
    }
#pragma unroll
    for (int fm = 0; fm < 4; ++fm)
      *(f32x4*)&S[(wid * 4 + fm) * 256 + lane * 4] = acc2[fm];
    __syncthreads();
    f32x4 rv = *(const f32x4*)&S[(wid) * 256 + lane * 4];
#pragma unroll
    for (int w = 1; w < 4; ++w)
      rv += *(const f32x4*)&S[(w * 4 + wid) * 256 + lane * 4];
    float bo = bout[j0 + lrow];
    float m = fmaxf(fmaxf(rv[0], rv[1]), fmaxf(rv[2], rv[3])) + bo;
    __syncthreads();
    S[(wid * 4 + lgrp) * 16 + lrow] = m;
    __syncthreads();
    if (tid < 16) {
      float mx = S[tid];
#pragma unroll
      for (int s2 = 1; s2 < 16; ++s2) mx = fmaxf(mx, S[s2 * 16 + tid]);
      __hip_atomic_store(&pmax[(size_t)g * H_ + j0 + tid], mx, __ATOMIC_RELAXED, __HIP_MEMORY_SCOPE_AGENT);
    }
  }
  __syncthreads();
  if (tid == 0) set_flag(myflag, 4u);

  if (bid != 0) return;

  // ---- final: max over groups, 1024->2 dot, sigmoid ----
  if (wid == 0) {
    for (int g2 = 0; g2 < 4; ++g2) {
      for (;;) {
        u32 f = __hip_atomic_load(&flags[g2 * 64 + lane], __ATOMIC_RELAXED, __HIP_MEMORY_SCOPE_AGENT);
        if (__all((int)(f >= 4u))) break;
        __builtin_amdgcn_s_sleep(1);
      }
    }
  }
  asm volatile("" ::: "memory");
  __syncthreads();
  {
    int j4 = tid * 4;
    float s0 = 0.f, s1 = 0.f;
#pragma unroll
    for (int e = 0; e < 4; ++e) {
      float pv = pmax[j4 + e];
#pragma unroll
      for (int gg2 = 1; gg2 < 4; ++gg2) pv = fmaxf(pv, pmax[gg2 * H_ + j4 + e]);
      s0 += pv * Wlin[j4 + e];
      s1 += pv * Wlin[H_ + j4 + e];
    }
    S[tid] = s0; S[256 + tid] = s1;
    __syncthreads();
    for (int s2 = 128; s2 > 0; s2 >>= 1) {
      if (tid < s2) { S[tid] += S[tid + s2]; S[256 + tid] += S[256 + tid + s2]; }
      __syncthreads();
    }
    if (tid == 0) {
      out[0] = sigf(S[0] + blin[0]);
      out[1] = sigf(S[256] + blin[1]);
    }
  }
}

extern "C" void kernel_launch(void* const* d_in, const int* in_sizes, int n_in,
                              void* d_out, int out_size, void* d_ws, size_t ws_size,
                              hipStream_t stream) {
  const int*   paths   = (const int*)d_in[0];
  const int*   lengths = (const int*)d_in[1];
  const float* emb     = (const float*)d_in[2];
  const float* Wih     = (const float*)d_in[3];
  const float* Whh     = (const float*)d_in[4];
  const float* bih     = (const float*)d_in[5];
  const float* bhh     = (const float*)d_in[6];
  const float* Win     = (const float*)d_in[7];
  const float* bin     = (const float*)d_in[8];
  const float* Wout    = (const float*)d_in[9];
  const float* bout    = (const float*)d_in[10];
  const float* Wlin    = (const float*)d_in[11];
  const float* blin    = (const float*)d_in[12];
  float* out = (float*)d_out;

  char* ws = (char*)d_ws;
  u32*   flags  = (u32*)  (ws);                  //      1,024 (4 groups x 64 packed flags)
  float* pmax   = (float*)(ws + 4096);           //     16,384
  u16*   X      = (u16*)  (ws + 32768);          // 16,777,216
  u16*   Hbuf   = (u16*)  (ws + 16810240);       // 65 x 524,288 = 34,078,720
  u16*   vbuf   = (u16*)  (ws + 50888960);       //    524,288   (total ~51.4 MB)

  hipMemsetAsync(flags, 0, 1024, stream);
  tagger_net<<<256, 256, 0, stream>>>(paths, lengths, emb, Wih, Whh, bih, bhh,
                                      Win, bin, Wout, bout, Wlin, blin,
                                      X, Hbuf, vbuf, pmax, flags, out);
}

// Round 14
// 553.896 us; speedup vs baseline: 2.3275x; 1.1120x over previous
//
#include <hip/hip_runtime.h>
#include <stdint.h>

typedef unsigned short u16;
typedef unsigned int u32;
typedef __attribute__((ext_vector_type(8))) short s16x8;
typedef __attribute__((ext_vector_type(4))) float f32x4;

#define P_ 256
#define L_ 64
#define IDIM 512
#define H_ 1024
#define PH (P_ * H_)

__device__ __forceinline__ u16 f2bf(float f){union{float f;u32 u;}v;v.f=f;u32 u=v.u;return (u16)((u+0x7FFFu+((u>>16)&1u))>>16);}
__device__ __forceinline__ float sigf(float x){return 1.0f/(1.0f+__expf(-x));}
__device__ __forceinline__ float tanhf_(float x){return 1.0f-2.0f/(__expf(2.0f*x)+1.0f);}

__device__ __forceinline__ s16x8 pack8v(float4 a, float4 b){
  s16x8 r;
  r[0]=(short)f2bf(a.x); r[1]=(short)f2bf(a.y); r[2]=(short)f2bf(a.z); r[3]=(short)f2bf(a.w);
  r[4]=(short)f2bf(b.x); r[5]=(short)f2bf(b.y); r[6]=(short)f2bf(b.z); r[7]=(short)f2bf(b.w);
  return r;
}
__device__ __forceinline__ s16x8 pack8(const float* s){
  return pack8v(*(const float4*)s, *(const float4*)(s+4));
}
// 16B write-through store (bypasses L2 -> coherent at IF$)
__device__ __forceinline__ void st16_coh(u16* addr, s16x8 v){
  asm volatile("global_store_dwordx4 %0, %1, off sc0 sc1" :: "v"(addr), "v"(v) : "memory");
}
// paired 2-lane bf16 -> one 32-bit write-through store
__device__ __forceinline__ void st_pair(u16* addr, float hv, int lane){
  u32 b = (u32)f2bf(hv);
  u32 other = __shfl_xor(b, 1);
  if ((lane & 1) == 0) {
    u32 w = b | (other << 16);
    __hip_atomic_store((u32*)addr, w, __ATOMIC_RELAXED, __HIP_MEMORY_SCOPE_AGENT);
  }
}
__device__ __forceinline__ void set_flag(u32* f, u32 v){
  __hip_atomic_store(f, v, __ATOMIC_RELAXED, __HIP_MEMORY_SCOPE_AGENT);
}
// wave0: lane l polls flag[l] of own group (packed line; one coalesced load/iter)
__device__ __forceinline__ void poll_flags(u32* fg, u32 target, int wid, int lane){
  if (wid == 0) {
    for (;;) {
      u32 f = __hip_atomic_load(&fg[lane], __ATOMIC_RELAXED, __HIP_MEMORY_SCOPE_AGENT);
      if (__all((int)(f >= target))) break;
      __builtin_amdgcn_s_sleep(1);
    }
  }
  asm volatile("" ::: "memory");
  __syncthreads();
}
// lgkm-only barrier (LDS writes drained; VMEM loads stay in flight) — rule #18 fenced
__device__ __forceinline__ void lds_barrier(){
  asm volatile("s_waitcnt lgkmcnt(0)" ::: "memory");
  __builtin_amdgcn_sched_barrier(0);
  __builtin_amdgcn_s_barrier();
  __builtin_amdgcn_sched_barrier(0);
}

// Persistent kernel: 256 blocks x 512 threads = 4 path-groups x 64 unit-blocks.
// 8 waves/block, per-wave K-split = 192 (6 chunks): breg 96 VGPR/wave -> deep load
// pipelining headroom + 2 waves/SIMD co-issue. XCD-clustered mapping (R9).
__global__ void __launch_bounds__(512, 1)
tagger_net(const int* __restrict__ paths, const int* __restrict__ lengths,
           const float* __restrict__ emb,
           const float* __restrict__ Wih, const float* __restrict__ Whh,
           const float* __restrict__ bih, const float* __restrict__ bhh,
           const float* __restrict__ Win, const float* __restrict__ bin,
           const float* __restrict__ Wout, const float* __restrict__ bout,
           const float* __restrict__ Wlin, const float* __restrict__ blin,
           u16* __restrict__ X, u16* __restrict__ Hbuf,
           u16* __restrict__ vbuf, float* __restrict__ pmax,
           u32* flags, float* __restrict__ out)
{
  __shared__ __align__(16) float S[16384];   // 64 KB reduction scratch (2 fn-rounds)
  const int tid  = threadIdx.x;
  const int wid  = tid >> 6, lane = tid & 63;
  const int lrow = lane & 15, lgrp = lane >> 4;
  const int bid  = blockIdx.x;
  const int g = bid & 3, jb = bid >> 2;      // XCD-clustered group mapping
  const int p0 = g * 64, j0 = jb * 16;
  u32* fgrp = flags + g * 64;
  u32* myflag = fgrp + jb;

  // ---- init: gather X[t=jb][p0..p0+63][:] (write-through); zero own Hbuf[0] chunk
  for (int it = 0; it < 8; ++it) {
    int e = (it * 512 + tid) * 8;
    int row = e >> 9, col = e & 511;
    int tok = paths[(p0 + row) * L_ + jb];
    const float* s = emb + (size_t)tok * IDIM + col;
    st16_coh(X + ((size_t)jb * P_ + p0 + row) * IDIM + col,
             pack8v(*(const float4*)s, *(const float4*)(s + 4)));
  }
  {
    int row = tid >> 3, cp = tid & 7;        // 512 u32 cells = 64 rows x 8 col-pairs
    __hip_atomic_store((u32*)&Hbuf[(size_t)(p0 + row) * H_ + j0 + cp * 2], 0u,
                       __ATOMIC_RELAXED, __HIP_MEMORY_SCOPE_AGENT);
  }
  __syncthreads();                            // drains vmcnt of all waves
  if (tid == 0) set_flag(myflag, 1u);

  // ---- weights into registers: wave wid owns K chunks c = wid + 8*i (i=0..5) ----
  // i=0,1 -> X chunks (k<512); i=2..5 -> H chunks
  s16x8 breg[6][4];
#pragma unroll
  for (int i = 0; i < 6; ++i) {
    const int kg = (wid + 8 * i) * 32 + lgrp * 8;
#pragma unroll
    for (int fn = 0; fn < 4; ++fn) {
      const int n = fn * H_ + j0 + lrow;
      const float* src = (kg < IDIM) ? (Wih + (size_t)n * IDIM + kg)
                                     : (Whh + (size_t)n * H_ + (kg - IDIM));
      breg[i][fn] = pack8(src);
    }
  }

  // epilogue ownership: waves 0-3 own row-frag fm = wid (16 rows each)
  const int prow = p0 + (wid & 3) * 16 + lgrp * 4;
  int lenr[4]; float biasv[4];
#pragma unroll
  for (int r2 = 0; r2 < 4; ++r2) lenr[r2] = lengths[prow + r2];
#pragma unroll
  for (int fn = 0; fn < 4; ++fn) {
    int n = fn * H_ + j0 + lrow;
    biasv[fn] = bih[n] + bhh[n];
  }
  float cst[4] = {0.f,0.f,0.f,0.f}, hst[4] = {0.f,0.f,0.f,0.f};

  poll_flags(fgrp, 1u, wid, lane);            // init done (own group)

  const size_t aX = (size_t)(p0 + lrow) * IDIM + lgrp * 8;
  const size_t aH = (size_t)(p0 + lrow) * H_   + lgrp * 8;

  s16x8 fx[2][4];
#define LOADX(T) do { \
    const u16* Xt_ = X + (size_t)(T) * (P_ * IDIM) + aX; \
    _Pragma("unroll") \
    for (int i_ = 0; i_ < 2; ++i_) { \
      const int k0_ = (wid + 8 * i_) * 32; \
      _Pragma("unroll") \
      for (int fm_ = 0; fm_ < 4; ++fm_) \
        fx[i_][fm_] = *(const s16x8*)(Xt_ + (size_t)fm_ * (16 * IDIM) + k0_); \
    } } while (0)

  LOADX(0);

  for (int t = 0; t < L_; ++t) {
    const u16* Hr = Hbuf + (size_t)t * PH;
    u16*       Hw = Hbuf + (size_t)(t + 1) * PH;

    f32x4 acc[4][4];
#pragma unroll
    for (int a = 0; a < 4; ++a)
#pragma unroll
      for (int b = 0; b < 4; ++b)
#pragma unroll
        for (int e = 0; e < 4; ++e) acc[a][b][e] = 0.0f;

    // ---- X phase (pre-poll; hides sibling skew) ----
#pragma unroll
    for (int i = 0; i < 2; ++i)
#pragma unroll
      for (int fm = 0; fm < 4; ++fm)
#pragma unroll
        for (int fn = 0; fn < 4; ++fn)
          acc[fm][fn] = __builtin_amdgcn_mfma_f32_16x16x32_bf16(fx[i][fm], breg[i][fn], acc[fm][fn], 0, 0, 0);

    // ---- wait for Hbuf[t] ----
    poll_flags(fgrp, (u32)(t + 1), wid, lane);

    // ---- H phase: issue ALL 4 chunk-batches (VGPR headroom), then MFMA ----
    const u16* Hp = Hr + aH;
    s16x8 fhA[2][4], fhB[2][4];
#pragma unroll
    for (int i = 0; i < 2; ++i) {
      const int kh = wid * 32 + i * 256;      // chunks i=2,3: kh = wid*32 + {0,256}
#pragma unroll
      for (int fm = 0; fm < 4; ++fm)
        fhA[i][fm] = *(const s16x8*)(Hp + (size_t)fm * (16 * H_) + kh);
    }
#pragma unroll
    for (int i = 0; i < 2; ++i) {
      const int kh = wid * 32 + 512 + i * 256; // chunks i=4,5
#pragma unroll
      for (int fm = 0; fm < 4; ++fm)
        fhB[i][fm] = *(const s16x8*)(Hp + (size_t)fm * (16 * H_) + kh);
    }
#pragma unroll
    for (int i = 0; i < 2; ++i)
#pragma unroll
      for (int fm = 0; fm < 4; ++fm)
#pragma unroll
        for (int fn = 0; fn < 4; ++fn)
          acc[fm][fn] = __builtin_amdgcn_mfma_f32_16x16x32_bf16(fhA[i][fm], breg[2 + i][fn], acc[fm][fn], 0, 0, 0);
    { const int tp1 = (t < L_ - 1) ? (t + 1) : (L_ - 1); LOADX(tp1); }
#pragma unroll
    for (int i = 0; i < 2; ++i)
#pragma unroll
      for (int fm = 0; fm < 4; ++fm)
#pragma unroll
        for (int fn = 0; fn < 4; ++fn)
          acc[fm][fn] = __builtin_amdgcn_mfma_f32_16x16x32_bf16(fhB[i][fm], breg[4 + i][fn], acc[fm][fn], 0, 0, 0);

    // ---- 8-way reduction, two fn-rounds over 64 KB LDS ----
    f32x4 red[4];
#pragma unroll
    for (int rr = 0; rr < 2; ++rr) {
#pragma unroll
      for (int fm = 0; fm < 4; ++fm)
#pragma unroll
        for (int q = 0; q < 2; ++q)
          *(f32x4*)&S[(wid * 8 + fm * 2 + q) * 256 + lane * 4] = acc[fm][2 * rr + q];
      lds_barrier();
      if (wid < 4) {
#pragma unroll
        for (int q = 0; q < 2; ++q) {
          f32x4 v = *(const f32x4*)&S[(wid * 2 + q) * 256 + lane * 4];
#pragma unroll
          for (int s = 1; s < 8; ++s)
            v += *(const f32x4*)&S[(s * 8 + wid * 2 + q) * 256 + lane * 4];
          red[2 * rr + q] = v;
        }
      }
      lds_barrier();                          // S reusable for next round
    }

    // ---- gate epilogue (waves 0-3), write-through H ----
    if (wid < 4) {
#pragma unroll
      for (int r2 = 0; r2 < 4; ++r2) {
        if (t < lenr[r2]) {
          float gi = red[0][r2] + biasv[0];
          float gf = red[1][r2] + biasv[1];
          float gg = red[2][r2] + biasv[2];
          float go = red[3][r2] + biasv[3];
          float cn = sigf(gf) * cst[r2] + sigf(gi) * tanhf_(gg);
          cst[r2] = cn;
          hst[r2] = sigf(go) * tanhf_(cn);
        }
        st_pair(&Hw[(size_t)(prow + r2) * H_ + j0 + lrow], hst[r2], lane);
      }
    }
    __syncthreads();                          // drain all stores before flag
    if (tid == 0) set_flag(myflag, (u32)(t + 2));
  }

  // ================= tail =================
  const u16* hfin = Hbuf + (size_t)L_ * PH;
  poll_flags(fgrp, 65u, wid, lane);

  // ---- v = h@Wv^T + bv (8-way K-split, single 32 KB dump) ----
  {
    f32x4 acc2[4];
#pragma unroll
    for (int a = 0; a < 4; ++a)
#pragma unroll
      for (int e = 0; e < 4; ++e) acc2[a][e] = 0.0f;
    const u16* hp = hfin + aH;
    const float* wv = Win + (size_t)(2 * H_ + j0 + lrow) * H_;
#pragma unroll
    for (int ic = 0; ic < 4; ++ic) {
      const int k0 = wid * 128 + ic * 32;
      s16x8 fbv = pack8(wv + k0 + lgrp * 8);
#pragma unroll
      for (int fm = 0; fm < 4; ++fm) {
        s16x8 fav = *(const s16x8*)(hp + (size_t)fm * (16 * H_) + k0);
        acc2[fm] = __builtin_amdgcn_mfma_f32_16x16x32_bf16(fav, fbv, acc2[fm], 0, 0, 0);
      }
    }
#pragma unroll
    for (int fm = 0; fm < 4; ++fm)
      *(f32x4*)&S[(wid * 4 + fm) * 256 + lane * 4] = acc2[fm];
    __syncthreads();
    if (wid < 4) {
      f32x4 rv = *(const f32x4*)&S[(wid) * 256 + lane * 4];
#pragma unroll
      for (int s = 1; s < 8; ++s)
        rv += *(const f32x4*)&S[(s * 4 + wid) * 256 + lane * 4];
      float bvj = bin[2 * H_ + j0 + lrow];
#pragma unroll
      for (int r2 = 0; r2 < 4; ++r2)
        st_pair(&vbuf[(size_t)(prow + r2) * H_ + j0 + lrow], rv[r2] + bvj, lane);
    }
  }
  __syncthreads();
  if (tid == 0) set_flag(myflag, 66u);
  poll_flags(fgrp, 66u, wid, lane);

  // ---- attn = v@Wout^T + bout, per-block max over own 64 rows ----
  {
    f32x4 acc2[4];
#pragma unroll
    for (int a = 0; a < 4; ++a)
#pragma unroll
      for (int e = 0; e < 4; ++e) acc2[a][e] = 0.0f;
    const u16* vp = vbuf + aH;
    const float* wo = Wout + (size_t)(j0 + lrow) * H_;
#pragma unroll
    for (int ic = 0; ic < 4; ++ic) {
      const int k0 = wid * 128 + ic * 32;
      s16x8 fbv = pack8(wo + k0 + lgrp * 8);
#pragma unroll
      for (int fm = 0; fm < 4; ++fm) {
        s16x8 fav = *(const s16x8*)(vp + (size_t)fm * (16 * H_) + k0);
        acc2[fm] = __builtin_amdgcn_mfma_f32_16x16x32_bf16(fav, fbv, acc2[fm], 0, 0, 0);
      }
    }
#pragma unroll
    for (int fm = 0; fm < 4; ++fm)
      *(f32x4*)&S[(wid * 4 + fm) * 256 + lane * 4] = acc2[fm];
    __syncthreads();
    if (wid < 4) {
      f32x4 rv = *(const f32x4*)&S[(wid) * 256 + lane * 4];
#pragma unroll
      for (int s = 1; s < 8; ++s)
        rv += *(const f32x4*)&S[(s * 4 + wid) * 256 + lane * 4];
      float bo = bout[j0 + lrow];
      float m = fmaxf(fmaxf(rv[0], rv[1]), fmaxf(rv[2], rv[3])) + bo;
      __syncthreads();
      S[(wid * 4 + lgrp) * 16 + lrow] = m;
    } else {
      __syncthreads();
    }
    __syncthreads();
    if (tid < 16) {
      float mx = S[tid];
#pragma unroll
      for (int s2 = 1; s2 < 16; ++s2) mx = fmaxf(mx, S[s2 * 16 + tid]);
      __hip_atomic_store(&pmax[(size_t)g * H_ + j0 + tid], mx, __ATOMIC_RELAXED, __HIP_MEMORY_SCOPE_AGENT);
    }
  }
  __syncthreads();
  if (tid == 0) set_flag(myflag, 67u);

  if (bid != 0) return;

  // ---- final: max over groups, 1024->2 dot, sigmoid (512 threads, 2 elems each) ----
  if (wid == 0) {
    for (int g2 = 0; g2 < 4; ++g2) {
      for (;;) {
        u32 f = __hip_atomic_load(&flags[g2 * 64 + lane], __ATOMIC_RELAXED, __HIP_MEMORY_SCOPE_AGENT);
        if (__all((int)(f >= 67u))) break;
        __builtin_amdgcn_s_sleep(1);
      }
    }
  }
  asm volatile("" ::: "memory");
  __syncthreads();
  {
    int j2 = tid * 2;
    float s0 = 0.f, s1 = 0.f;
#pragma unroll
    for (int e = 0; e < 2; ++e) {
      float pv = pmax[j2 + e];
#pragma unroll
      for (int gg2 = 1; gg2 < 4; ++gg2) pv = fmaxf(pv, pmax[gg2 * H_ + j2 + e]);
      s0 += pv * Wlin[j2 + e];
      s1 += pv * Wlin[H_ + j2 + e];
    }
    S[tid] = s0; S[512 + tid] = s1;
    __syncthreads();
    for (int s2 = 256; s2 > 0; s2 >>= 1) {
      if (tid < s2) { S[tid] += S[tid + s2]; S[512 + tid] += S[512 + tid + s2]; }
      __syncthreads();
    }
    if (tid == 0) {
      out[0] = sigf(S[0] + blin[0]);
      out[1] = sigf(S[512] + blin[1]);
    }
  }
}

extern "C" void kernel_launch(void* const* d_in, const int* in_sizes, int n_in,
                              void* d_out, int out_size, void* d_ws, size_t ws_size,
                              hipStream_t stream) {
  const int*   paths   = (const int*)d_in[0];
  const int*   lengths = (const int*)d_in[1];
  const float* emb     = (const float*)d_in[2];
  const float* Wih     = (const float*)d_in[3];
  const float* Whh     = (const float*)d_in[4];
  const float* bih     = (const float*)d_in[5];
  const float* bhh     = (const float*)d_in[6];
  const float* Win     = (const float*)d_in[7];
  const float* bin     = (const float*)d_in[8];
  const float* Wout    = (const float*)d_in[9];
  const float* bout    = (const float*)d_in[10];
  const float* Wlin    = (const float*)d_in[11];
  const float* blin    = (const float*)d_in[12];
  float* out = (float*)d_out;

  char* ws = (char*)d_ws;
  u32*   flags  = (u32*)  (ws);                  //      1,024 (4 groups x 64 packed flags)
  float* pmax   = (float*)(ws + 4096);           //     16,384
  u16*   X      = (u16*)  (ws + 32768);          // 16,777,216
  u16*   Hbuf   = (u16*)  (ws + 16810240);       // 65 x 524,288 = 34,078,720
  u16*   vbuf   = (u16*)  (ws + 50888960);       //    524,288   (total ~51.4 MB)

  hipMemsetAsync(flags, 0, 1024, stream);
  tagger_net<<<256, 512, 0, stream>>>(paths, lengths, emb, Wih, Whh, bih, bhh,
                                      Win, bin, Wout, bout, Wlin, blin,
                                      X, Hbuf, vbuf, pmax, flags, out);
}